// Round 2
// baseline (3884.155 us; speedup 1.0000x reference)
//
#include <hip/hip_runtime.h>
#include <hip/hip_bf16.h>
#include <math.h>

#define B_ 2
#define N_ 384
#define D_ 128
#define LAT_ 256
#define NPOS_ 33
#define ROWS_ (B_*N_)   // 768
#define SUBS_ 4         // n-subrows per attn block (block = SUBS_*128 threads)

// ---------------- encode: f[r,d] = feats[r]*W[d] + b[d] ----------------
__global__ __launch_bounds__(256) void enc_kernel(const float* __restrict__ feats,
                           const float* __restrict__ W,
                           const float* __restrict__ bias,
                           float* __restrict__ f) {
    int i = blockIdx.x*256 + threadIdx.x;    // over ROWS_*D_
    if (i >= ROWS_*D_) return;
    int r = i >> 7, d = i & 127;
    f[i] = feats[r]*W[d] + bias[d];
}

// ---------------- qkv: per row r, thread d does 3 dot-128 ----------------
__global__ __launch_bounds__(128) void qkv_kernel(const float* __restrict__ f,
    const float* __restrict__ Wq, const float* __restrict__ Wk, const float* __restrict__ Wv,
    float* __restrict__ q, float* __restrict__ k, float* __restrict__ v) {
    __shared__ float row[D_];
    int r = blockIdx.x, d = threadIdx.x;
    row[d] = f[r*D_+d];
    __syncthreads();
    float aq=0.f, ak=0.f, av=0.f;
    #pragma unroll 8
    for (int e=0;e<D_;e++){
        float x = row[e];
        aq += Wq[d*D_+e]*x;
        ak += Wk[d*D_+e]*x;
        av += Wv[d*D_+e]*x;
    }
    q[r*D_+d]=aq; k[r*D_+d]=ak; v[r*D_+d]=av;
}

// ---------------- attention block: one workgroup per (b,m) row ----------------
// SUBS_*128 threads = SUBS_ n-subrows x 128 channels. Weights live in LDS,
// transposed so lane-consecutive channel reads are bank-conflict-free.
// Softmax over n is streamed (unnormalized exp; logits bounded O(1) for this
// data/scale, no max subtraction needed), state (s,r) per (sub,d) in
// registers, merged at end. LDS ~146 KB -> 1 block/CU; 512 threads = 8 waves.
__global__ __launch_bounds__(SUBS_*128) void attn_kernel(
    const float* __restrict__ xyz,   // [B,N,3]  (x4 = 4*xyz applied on the fly)
    const float* __restrict__ f,     // [ROWS_,D_]
    const float* __restrict__ qb, const float* __restrict__ kb, const float* __restrict__ vb,
    const float* __restrict__ Wpe, const float* __restrict__ bpe,
    const float* __restrict__ Wg1, const float* __restrict__ bg1,
    const float* __restrict__ Wg2, const float* __restrict__ bg2,
    float* __restrict__ gout)        // [ROWS_,D_] pre-BN (res + f)
{
    __shared__ float sWpeT[NPOS_][D_];   // 16.5 KB
    __shared__ float sWg1T[D_][D_];      // 64 KB
    __shared__ float sWg2T[D_][D_];      // 64 KB
    __shared__ float sParts[SUBS_][NPOS_];
    __shared__ float sEdges[SUBS_][D_];
    __shared__ float sH[SUBS_][D_];

    const int t   = threadIdx.x;
    const int row = blockIdx.x;          // b*N_+m
    const int b   = row / N_;
    const int sub = t >> 7;
    const int d   = t & 127;

    // stage weights (transposed) into LDS
    for (int idx = t; idx < D_*D_; idx += SUBS_*128) {
        int dd = idx >> 7, e = idx & 127;
        sWg1T[e][dd] = Wg1[idx];
        sWg2T[e][dd] = Wg2[idx];
    }
    for (int idx = t; idx < D_*NPOS_; idx += SUBS_*128) {
        int dd = idx / NPOS_, p = idx - dd*NPOS_;
        sWpeT[p][dd] = Wpe[idx];
    }

    const float q_reg   = qb[row*D_+d];
    const float bg1_reg = bg1[d];
    const float bg2_reg = bg2[d];
    const float bpe_reg = bpe[d];
    const float x4m0 = 4.f*xyz[row*3+0];
    const float x4m1 = 4.f*xyz[row*3+1];
    const float x4m2 = 4.f*xyz[row*3+2];

    float s_state = 0.f, r_state = 0.f;
    __syncthreads();

    const float FR0=1.0f, FR1=8.75f, FR2=16.5f, FR3=24.25f, FR4=32.0f; // linspace(1,32,5)

    for (int n0 = 0; n0 < N_; n0 += SUBS_) {
        const int n    = n0 + sub;
        const int nrow = b*N_ + n;
        // ---- positional parts (33 values per sub-row) ----
        if (d < NPOS_) {
            float pd0 = x4m0 - 4.f*xyz[nrow*3+0];
            float pd1 = x4m1 - 4.f*xyz[nrow*3+1];
            float pd2 = x4m2 - 4.f*xyz[nrow*3+2];
            int p = d;
            float val;
            if (p < 3) {
                val = (p==0)?pd0:((p==1)?pd1:pd2);
            } else {
                int qq = p - 3;
                int fi = qq / 6;
                int rem = qq - fi*6;
                int j = (rem >= 3) ? rem-3 : rem;
                float pdj = (j==0)?pd0:((j==1)?pd1:pd2);
                float fr = (fi==0)?FR0:((fi==1)?FR1:((fi==2)?FR2:((fi==3)?FR3:FR4)));
                float a = pdj * fr;
                val = (rem < 3) ? __sinf(a) : __cosf(a);
            }
            sParts[sub][p] = val;
        }
        __syncthreads();
        // ---- pos = parts @ WpeT + bpe; edges = q - k + pos ----
        float pos = bpe_reg;
        #pragma unroll
        for (int p = 0; p < NPOS_; p++) pos += sWpeT[p][d] * sParts[sub][p];
        float edge = q_reg - kb[nrow*D_+d] + pos;
        sEdges[sub][d] = edge;
        __syncthreads();
        // ---- h = relu(edges @ Wg1T + bg1) ----
        float h = bg1_reg;
        #pragma unroll 16
        for (int e=0;e<D_;e++) h += sWg1T[e][d]*sEdges[sub][e];
        h = fmaxf(h, 0.f);
        sH[sub][d] = h;
        __syncthreads();
        // ---- logit = h @ Wg2T + bg2; streamed softmax update ----
        float lg = bg2_reg;
        #pragma unroll 16
        for (int e=0;e<D_;e++) lg += sWg2T[e][d]*sH[sub][e];
        float w = __expf(lg);
        s_state += w;
        r_state += w * (vb[nrow*D_+d] + pos);
        __syncthreads();  // protect sParts/sEdges/sH before next iter overwrite
    }

    // merge the SUBS_ sub-states (reuse sEdges/sH)
    sEdges[sub][d] = s_state;
    sH[sub][d]     = r_state;
    __syncthreads();
    if (sub == 0) {
        float s = 0.f, r = 0.f;
        #pragma unroll
        for (int u = 0; u < SUBS_; u++) { s += sEdges[u][d]; r += sH[u][d]; }
        gout[row*D_+d] = r/s + f[row*D_+d];
    }
}

// ---------------- batchnorm (train-mode batch stats) per channel ----------------
__global__ __launch_bounds__(256) void bn_kernel(const float* __restrict__ g,
    const float* __restrict__ gamma, const float* __restrict__ beta,
    float* __restrict__ fout)
{
    __shared__ float ssum[256], ssq[256];
    int d = blockIdx.x, t = threadIdx.x;
    float s=0.f, sq=0.f;
    for (int r=t; r<ROWS_; r+=256){ float x = g[r*D_+d]; s+=x; sq+=x*x; }
    ssum[t]=s; ssq[t]=sq; __syncthreads();
    for (int off=128; off>0; off>>=1){
        if (t<off){ ssum[t]+=ssum[t+off]; ssq[t]+=ssq[t+off]; }
        __syncthreads();
    }
    float mean = ssum[0]*(1.f/ROWS_);
    float var  = ssq[0]*(1.f/ROWS_) - mean*mean;
    float rs   = rsqrtf(var + 1e-5f);
    float ga = gamma[d], be = beta[d];
    for (int r=t; r<ROWS_; r+=256){
        fout[r*D_+d] = (g[r*D_+d]-mean)*rs*ga + be;
    }
}

// ---------------- elementwise MLP: gout = f + relu(W2@relu(W1@f+b1)+b2) ----------------
__global__ __launch_bounds__(128) void em_kernel(const float* __restrict__ f,
    const float* __restrict__ W1, const float* __restrict__ b1,
    const float* __restrict__ W2, const float* __restrict__ b2,
    float* __restrict__ gout)
{
    __shared__ float row[D_], y1[D_];
    int r = blockIdx.x, d = threadIdx.x;
    row[d] = f[r*D_+d]; __syncthreads();
    float a = b1[d];
    #pragma unroll 8
    for (int e=0;e<D_;e++) a += W1[d*D_+e]*row[e];
    y1[d] = fmaxf(a,0.f); __syncthreads();
    float a2 = b2[d];
    #pragma unroll 8
    for (int e=0;e<D_;e++) a2 += W2[d*D_+e]*y1[e];
    a2 = fmaxf(a2,0.f);
    gout[r*D_+d] = row[d] + a2;
}

// ---------------- final head: e = relu(f@W1.T+b1)@W2.T+b2 ----------------
__global__ __launch_bounds__(256) void final_kernel(const float* __restrict__ f,
    const float* __restrict__ W1, const float* __restrict__ b1,
    const float* __restrict__ W2, const float* __restrict__ b2,
    float* __restrict__ e_ws)
{
    __shared__ float row[D_];
    __shared__ float h1[LAT_];
    int r = blockIdx.x, t = threadIdx.x;
    if (t < D_) row[t] = f[r*D_+t];
    __syncthreads();
    float a = b1[t];
    #pragma unroll 8
    for (int e=0;e<D_;e++) a += W1[t*D_+e]*row[e];
    h1[t] = fmaxf(a,0.f);
    __syncthreads();
    float a2 = b2[t];
    #pragma unroll 8
    for (int e=0;e<LAT_;e++) a2 += W2[t*LAT_+e]*h1[e];
    e_ws[r*LAT_+t] = a2;
}

// ---------------- max over points ----------------
__global__ __launch_bounds__(256) void maxred_kernel(const float* __restrict__ e_ws,
                                                     float* __restrict__ out)
{
    int b = blockIdx.x, l = threadIdx.x;
    float m = -INFINITY;
    for (int n=0;n<N_;n++) m = fmaxf(m, e_ws[(b*N_+n)*LAT_+l]);
    out[b*LAT_+l] = m;
}

extern "C" void kernel_launch(void* const* d_in, const int* in_sizes, int n_in,
                              void* d_out, int out_size, void* d_ws, size_t ws_size,
                              hipStream_t stream) {
    (void)in_sizes; (void)n_in; (void)out_size; (void)ws_size;
    const float* xyz    = (const float*)d_in[0];
    const float* feats  = (const float*)d_in[1];
    const float* enc_W  = (const float*)d_in[2];
    const float* enc_b  = (const float*)d_in[3];
    const float* tb_Wq  = (const float*)d_in[4];
    const float* tb_Wk  = (const float*)d_in[5];
    const float* tb_Wv  = (const float*)d_in[6];
    const float* tb_Wg1 = (const float*)d_in[7];
    const float* tb_bg1 = (const float*)d_in[8];
    const float* tb_Wg2 = (const float*)d_in[9];
    const float* tb_bg2 = (const float*)d_in[10];
    const float* tb_Wpe = (const float*)d_in[11];
    const float* tb_bpe = (const float*)d_in[12];
    const float* tb_gamma = (const float*)d_in[13];
    const float* tb_beta  = (const float*)d_in[14];
    const float* em_W1  = (const float*)d_in[15];
    const float* em_b1  = (const float*)d_in[16];
    const float* em_W2  = (const float*)d_in[17];
    const float* em_b2  = (const float*)d_in[18];
    const float* em_gamma = (const float*)d_in[19];
    const float* em_beta  = (const float*)d_in[20];
    const float* fcf_W1 = (const float*)d_in[21];
    const float* fcf_b1 = (const float*)d_in[22];
    const float* fcf_W2 = (const float*)d_in[23];
    const float* fcf_b2 = (const float*)d_in[24];
    float* out = (float*)d_out;

    // workspace layout (floats)
    float* ws = (float*)d_ws;
    float* fbuf = ws;                      // ROWS_*D_
    float* gbuf = fbuf + ROWS_*D_;         // ROWS_*D_
    float* qbuf = gbuf + ROWS_*D_;
    float* kbuf = qbuf + ROWS_*D_;
    float* vbuf = kbuf + ROWS_*D_;
    float* ebuf = vbuf + ROWS_*D_;         // ROWS_*LAT_

    enc_kernel<<<(ROWS_*D_+255)/256, 256, 0, stream>>>(feats, enc_W, enc_b, fbuf);

    for (int i = 0; i < 3; i++) {
        const float* Wq  = tb_Wq  + i*D_*D_;
        const float* Wk  = tb_Wk  + i*D_*D_;
        const float* Wv  = tb_Wv  + i*D_*D_;
        const float* Wg1 = tb_Wg1 + i*D_*D_;
        const float* bg1 = tb_bg1 + i*D_;
        const float* Wg2 = tb_Wg2 + i*D_*D_;
        const float* bg2 = tb_bg2 + i*D_;
        const float* Wpe = tb_Wpe + i*D_*NPOS_;
        const float* bpe = tb_bpe + i*D_;

        qkv_kernel<<<ROWS_, 128, 0, stream>>>(fbuf, Wq, Wk, Wv, qbuf, kbuf, vbuf);
        attn_kernel<<<ROWS_, SUBS_*128, 0, stream>>>(xyz, fbuf, qbuf, kbuf, vbuf,
                                               Wpe, bpe, Wg1, bg1, Wg2, bg2, gbuf);
        bn_kernel<<<D_, 256, 0, stream>>>(gbuf, tb_gamma + i*D_, tb_beta + i*D_, fbuf);

        if (i > 0) {
            int j = i - 1;
            em_kernel<<<ROWS_, 128, 0, stream>>>(fbuf, em_W1 + j*D_*D_, em_b1 + j*D_,
                                                 em_W2 + j*D_*D_, em_b2 + j*D_, gbuf);
            bn_kernel<<<D_, 256, 0, stream>>>(gbuf, em_gamma + j*D_, em_beta + j*D_, fbuf);
        }
    }

    final_kernel<<<ROWS_, 256, 0, stream>>>(fbuf, fcf_W1, fcf_b1, fcf_W2, fcf_b2, ebuf);
    maxred_kernel<<<B_, 256, 0, stream>>>(ebuf, out);
}

// Round 3
// 617.030 us; speedup vs baseline: 6.2949x; 6.2949x over previous
//
#include <hip/hip_runtime.h>
#include <hip/hip_bf16.h>
#include <math.h>

#define B_ 2
#define N_ 384
#define D_ 128
#define LAT_ 256
#define NPOS_ 33
#define ROWS_ (B_*N_)   // 768

typedef __attribute__((ext_vector_type(8))) short bf16x8;
typedef __attribute__((ext_vector_type(4))) float f32x4;

#define MFMA(a,b,c) __builtin_amdgcn_mfma_f32_16x16x32_bf16((a),(b),(c),0,0,0)

__device__ __forceinline__ unsigned short f2bf(float x) {
    unsigned int u = __float_as_uint(x);
    u += 0x7FFFu + ((u >> 16) & 1u);   // round-to-nearest-even
    return (unsigned short)(u >> 16);
}

// ---------------- encode: f[r,d] = feats[r]*W[d] + b[d] ----------------
__global__ __launch_bounds__(256) void enc_kernel(const float* __restrict__ feats,
                           const float* __restrict__ W,
                           const float* __restrict__ bias,
                           float* __restrict__ f) {
    int i = blockIdx.x*256 + threadIdx.x;
    if (i >= ROWS_*D_) return;
    int r = i >> 7, d = i & 127;
    f[i] = feats[r]*W[d] + bias[d];
}

// ---------------- qkv ----------------
__global__ __launch_bounds__(128) void qkv_kernel(const float* __restrict__ f,
    const float* __restrict__ Wq, const float* __restrict__ Wk, const float* __restrict__ Wv,
    float* __restrict__ q, float* __restrict__ k, float* __restrict__ v) {
    __shared__ float row[D_];
    int r = blockIdx.x, d = threadIdx.x;
    row[d] = f[r*D_+d];
    __syncthreads();
    float aq=0.f, ak=0.f, av=0.f;
    #pragma unroll 8
    for (int e=0;e<D_;e++){
        float x = row[e];
        aq += Wq[d*D_+e]*x;
        ak += Wk[d*D_+e]*x;
        av += Wv[d*D_+e]*x;
    }
    q[r*D_+d]=aq; k[r*D_+d]=ak; v[r*D_+d]=av;
}

// ---------------- MFMA attention: one workgroup per (b,m) query row ----------------
// 512 thr = 8 waves. Wave w: rb = w>>2 (n-rowblock of 16), col-tiles ct0 = (w&3)*2, +1.
// Weights live as bf16 B-fragments in REGISTERS (loaded once from global fp32).
// Per n-tile of 32: parts->LDS(bf16,swz) -> pos GEMM (K=64 pad) -> edges->LDS(bf16,swz)
// -> Wg1 GEMM -> relu -> LDS -> Wg2 GEMM -> exp -> streamed softmax accumulate.
__global__ __launch_bounds__(512) void attn_mfma_kernel(
    const float* __restrict__ xyz, const float* __restrict__ f,
    const float* __restrict__ qb, const float* __restrict__ kb, const float* __restrict__ vb,
    const float* __restrict__ Wpe, const float* __restrict__ bpe,
    const float* __restrict__ Wg1, const float* __restrict__ bg1,
    const float* __restrict__ Wg2, const float* __restrict__ bg2,
    float* __restrict__ gout)
{
    __shared__ unsigned short sParts[32*64];   // bf16, swizzled, K-padded (p>=33 zero)
    __shared__ unsigned short sX[32*128];      // edges bf16, swizzled
    __shared__ unsigned short sH[32*128];      // h bf16, swizzled
    __shared__ float sK[32*132];               // +4 pad: breaks 4-way bank alias
    __shared__ float sV[32*132];
    __shared__ float sRed[4*128];              // [rb*2+{res,s}][d]

    const int t   = threadIdx.x;
    const int w   = t >> 6;
    const int l   = t & 63;
    const int lr  = l & 15;
    const int lg  = l >> 4;
    const int rb  = w >> 2;
    const int ct0 = (w & 3) * 2;

    const int row  = blockIdx.x;
    const int b    = row / N_;
    const int brow = b * N_;

    // ---- prologue: register B-fragments (bf16) + per-col scalars ----
    bf16x8 bWg1[2][4], bWg2[2][4], bWpe[2][2];
    float  bpe_c[2], bg1_c[2], bg2_c[2], q_c[2];

    #pragma unroll
    for (int ct = 0; ct < 2; ++ct) {
        const int dout = (ct0 + ct) * 16 + lr;
        #pragma unroll
        for (int kt = 0; kt < 4; ++kt) {
            const float* p1 = Wg1 + dout * D_ + kt * 32 + lg * 8;
            const float* p2 = Wg2 + dout * D_ + kt * 32 + lg * 8;
            float4 a0 = *(const float4*)(p1);
            float4 a1 = *(const float4*)(p1 + 4);
            float4 c0 = *(const float4*)(p2);
            float4 c1 = *(const float4*)(p2 + 4);
            bf16x8 v1, v2;
            v1[0]=(short)f2bf(a0.x); v1[1]=(short)f2bf(a0.y); v1[2]=(short)f2bf(a0.z); v1[3]=(short)f2bf(a0.w);
            v1[4]=(short)f2bf(a1.x); v1[5]=(short)f2bf(a1.y); v1[6]=(short)f2bf(a1.z); v1[7]=(short)f2bf(a1.w);
            v2[0]=(short)f2bf(c0.x); v2[1]=(short)f2bf(c0.y); v2[2]=(short)f2bf(c0.z); v2[3]=(short)f2bf(c0.w);
            v2[4]=(short)f2bf(c1.x); v2[5]=(short)f2bf(c1.y); v2[6]=(short)f2bf(c1.z); v2[7]=(short)f2bf(c1.w);
            bWg1[ct][kt] = v1;
            bWg2[ct][kt] = v2;
        }
        #pragma unroll
        for (int kt = 0; kt < 2; ++kt) {
            bf16x8 vv;
            #pragma unroll
            for (int e = 0; e < 8; ++e) {
                const int p = kt*32 + lg*8 + e;
                const float x = (p < NPOS_) ? Wpe[dout*NPOS_ + p] : 0.f;
                vv[e] = (short)f2bf(x);
            }
            bWpe[ct][kt] = vv;
        }
        bpe_c[ct] = bpe[dout];
        bg1_c[ct] = bg1[dout];
        bg2_c[ct] = bg2[dout];
        q_c[ct]   = qb[row*D_ + dout];
    }

    const float x4m0 = 4.f*xyz[row*3+0];
    const float x4m1 = 4.f*xyz[row*3+1];
    const float x4m2 = 4.f*xyz[row*3+2];

    // zero sParts once (K padding p=33..63 must stay 0)
    for (int i = t; i < 32*64/2; i += 512) ((unsigned int*)sParts)[i] = 0u;
    __syncthreads();

    float res_p[2] = {0.f, 0.f}, s_p[2] = {0.f, 0.f};

    for (int it = 0; it < N_/32; ++it) {
        const int n0 = it * 32;

        // ---- stage K/V tiles (coalesced float4) ----
        for (int s4 = t; s4 < 1024; s4 += 512) {
            const int n = s4 >> 5, c4 = s4 & 31;
            const float4 kk = *(const float4*)(kb + (brow + n0 + n)*D_ + c4*4);
            const float4 vv = *(const float4*)(vb + (brow + n0 + n)*D_ + c4*4);
            *(float4*)&sK[n*132 + c4*4] = kk;
            *(float4*)&sV[n*132 + c4*4] = vv;
        }
        // ---- parts[32][33] (each thread: p=j, p=j+16, j==0 also p=32) ----
        {
            const int n = t >> 4, j = t & 15;
            const int nr = (brow + n0 + n) * 3;
            const float pd0 = x4m0 - 4.f*xyz[nr+0];
            const float pd1 = x4m1 - 4.f*xyz[nr+1];
            const float pd2 = x4m2 - 4.f*xyz[nr+2];
            auto pval = [&](int p) -> float {
                if (p < 3) return p==0?pd0:(p==1?pd1:pd2);
                const int qq = p - 3;
                const int fi = qq / 6;
                int rem = qq - fi*6;
                bool is_sin = true;
                if (rem >= 3) { rem -= 3; is_sin = false; }
                const float pdj = rem==0?pd0:(rem==1?pd1:pd2);
                const float fr = fi==0?1.f:(fi==1?8.75f:(fi==2?16.5f:(fi==3?24.25f:32.f)));
                const float a = pdj * fr;
                return is_sin ? __sinf(a) : __cosf(a);
            };
            const int sw = (n & 7) << 3;
            sParts[(n*64 + j)      ^ sw] = f2bf(pval(j));
            sParts[(n*64 + j + 16) ^ sw] = f2bf(pval(j + 16));
            if (j == 0) sParts[(n*64 + 32) ^ sw] = f2bf(pval(32));
        }
        __syncthreads();

        // ---- pos GEMM (K=64) + edges = q - k + pos -> sX ----
        f32x4 pos[2];
        #pragma unroll
        for (int ct = 0; ct < 2; ++ct) {
            f32x4 acc = {0.f, 0.f, 0.f, 0.f};
            #pragma unroll
            for (int kt = 0; kt < 2; ++kt) {
                const int r16 = rb*16 + lr;
                const int idx = (r16*64 + kt*32 + lg*8) ^ ((r16 & 7) << 3);
                bf16x8 a = *(const bf16x8*)&sParts[idx];
                acc = MFMA(a, bWpe[ct][kt], acc);
            }
            #pragma unroll
            for (int r = 0; r < 4; ++r) acc[r] += bpe_c[ct];
            pos[ct] = acc;
        }
        #pragma unroll
        for (int ct = 0; ct < 2; ++ct) {
            const int d = (ct0 + ct)*16 + lr;
            #pragma unroll
            for (int r = 0; r < 4; ++r) {
                const int nl = rb*16 + lg*4 + r;
                const float e = pos[ct][r] + q_c[ct] - sK[nl*132 + d];
                sX[(nl*128 + d) ^ ((nl & 7) << 3)] = f2bf(e);
            }
        }
        __syncthreads();

        // ---- h = relu(edges @ Wg1^T + bg1) -> sH ----
        f32x4 hacc[2];
        hacc[0] = (f32x4){bg1_c[0], bg1_c[0], bg1_c[0], bg1_c[0]};
        hacc[1] = (f32x4){bg1_c[1], bg1_c[1], bg1_c[1], bg1_c[1]};
        #pragma unroll
        for (int kt = 0; kt < 4; ++kt) {
            const int r16 = rb*16 + lr;
            const int idx = (r16*128 + kt*32 + lg*8) ^ ((r16 & 7) << 3);
            bf16x8 a = *(const bf16x8*)&sX[idx];
            hacc[0] = MFMA(a, bWg1[0][kt], hacc[0]);
            hacc[1] = MFMA(a, bWg1[1][kt], hacc[1]);
        }
        #pragma unroll
        for (int ct = 0; ct < 2; ++ct) {
            const int d = (ct0 + ct)*16 + lr;
            #pragma unroll
            for (int r = 0; r < 4; ++r) {
                const int nl = rb*16 + lg*4 + r;
                sH[(nl*128 + d) ^ ((nl & 7) << 3)] = f2bf(fmaxf(hacc[ct][r], 0.f));
            }
        }
        __syncthreads();

        // ---- logits = h @ Wg2^T + bg2; streamed softmax accumulate ----
        f32x4 lacc[2];
        lacc[0] = (f32x4){bg2_c[0], bg2_c[0], bg2_c[0], bg2_c[0]};
        lacc[1] = (f32x4){bg2_c[1], bg2_c[1], bg2_c[1], bg2_c[1]};
        #pragma unroll
        for (int kt = 0; kt < 4; ++kt) {
            const int r16 = rb*16 + lr;
            const int idx = (r16*128 + kt*32 + lg*8) ^ ((r16 & 7) << 3);
            bf16x8 a = *(const bf16x8*)&sH[idx];
            lacc[0] = MFMA(a, bWg2[0][kt], lacc[0]);
            lacc[1] = MFMA(a, bWg2[1][kt], lacc[1]);
        }
        #pragma unroll
        for (int ct = 0; ct < 2; ++ct) {
            const int d = (ct0 + ct)*16 + lr;
            #pragma unroll
            for (int r = 0; r < 4; ++r) {
                const int nl = rb*16 + lg*4 + r;
                const float wgt = __expf(lacc[ct][r]);
                const float vp = sV[nl*132 + d] + pos[ct][r];
                res_p[ct] += wgt * vp;
                s_p[ct]   += wgt;
            }
        }
        __syncthreads();
    }

    // ---- cross-lane (n row-groups) then cross-rb reduce ----
    #pragma unroll
    for (int ct = 0; ct < 2; ++ct) {
        #pragma unroll
        for (int off = 16; off < 64; off <<= 1) {
            res_p[ct] += __shfl_xor(res_p[ct], off, 64);
            s_p[ct]   += __shfl_xor(s_p[ct], off, 64);
        }
    }
    if (lg < 2) {
        const int d = (ct0 + lg)*16 + lr;
        sRed[(rb*2+0)*128 + d] = (lg == 0) ? res_p[0] : res_p[1];
        sRed[(rb*2+1)*128 + d] = (lg == 0) ? s_p[0]   : s_p[1];
    }
    __syncthreads();
    if (t < D_) {
        const float rsum = sRed[t]       + sRed[2*128 + t];
        const float ssum = sRed[128 + t] + sRed[3*128 + t];
        gout[row*D_ + t] = rsum / ssum + f[row*D_ + t];
    }
}

// ---------------- batchnorm (train-mode batch stats) per channel ----------------
__global__ __launch_bounds__(256) void bn_kernel(const float* __restrict__ g,
    const float* __restrict__ gamma, const float* __restrict__ beta,
    float* __restrict__ fout)
{
    __shared__ float ssum[256], ssq[256];
    int d = blockIdx.x, t = threadIdx.x;
    float s=0.f, sq=0.f;
    for (int r=t; r<ROWS_; r+=256){ float x = g[r*D_+d]; s+=x; sq+=x*x; }
    ssum[t]=s; ssq[t]=sq; __syncthreads();
    for (int off=128; off>0; off>>=1){
        if (t<off){ ssum[t]+=ssum[t+off]; ssq[t]+=ssq[t+off]; }
        __syncthreads();
    }
    float mean = ssum[0]*(1.f/ROWS_);
    float var  = ssq[0]*(1.f/ROWS_) - mean*mean;
    float rs   = rsqrtf(var + 1e-5f);
    float ga = gamma[d], be = beta[d];
    for (int r=t; r<ROWS_; r+=256){
        fout[r*D_+d] = (g[r*D_+d]-mean)*rs*ga + be;
    }
}

// ---------------- elementwise MLP ----------------
__global__ __launch_bounds__(128) void em_kernel(const float* __restrict__ f,
    const float* __restrict__ W1, const float* __restrict__ b1,
    const float* __restrict__ W2, const float* __restrict__ b2,
    float* __restrict__ gout)
{
    __shared__ float row[D_], y1[D_];
    int r = blockIdx.x, d = threadIdx.x;
    row[d] = f[r*D_+d]; __syncthreads();
    float a = b1[d];
    #pragma unroll 8
    for (int e=0;e<D_;e++) a += W1[d*D_+e]*row[e];
    y1[d] = fmaxf(a,0.f); __syncthreads();
    float a2 = b2[d];
    #pragma unroll 8
    for (int e=0;e<D_;e++) a2 += W2[d*D_+e]*y1[e];
    a2 = fmaxf(a2,0.f);
    gout[r*D_+d] = row[d] + a2;
}

// ---------------- final head ----------------
__global__ __launch_bounds__(256) void final_kernel(const float* __restrict__ f,
    const float* __restrict__ W1, const float* __restrict__ b1,
    const float* __restrict__ W2, const float* __restrict__ b2,
    float* __restrict__ e_ws)
{
    __shared__ float row[D_];
    __shared__ float h1[LAT_];
    int r = blockIdx.x, t = threadIdx.x;
    if (t < D_) row[t] = f[r*D_+t];
    __syncthreads();
    float a = b1[t];
    #pragma unroll 8
    for (int e=0;e<D_;e++) a += W1[t*D_+e]*row[e];
    h1[t] = fmaxf(a,0.f);
    __syncthreads();
    float a2 = b2[t];
    #pragma unroll 8
    for (int e=0;e<LAT_;e++) a2 += W2[t*LAT_+e]*h1[e];
    e_ws[r*LAT_+t] = a2;
}

// ---------------- max over points ----------------
__global__ __launch_bounds__(256) void maxred_kernel(const float* __restrict__ e_ws,
                                                     float* __restrict__ out)
{
    int b = blockIdx.x, l = threadIdx.x;
    float m = -INFINITY;
    for (int n=0;n<N_;n++) m = fmaxf(m, e_ws[(b*N_+n)*LAT_+l]);
    out[b*LAT_+l] = m;
}

extern "C" void kernel_launch(void* const* d_in, const int* in_sizes, int n_in,
                              void* d_out, int out_size, void* d_ws, size_t ws_size,
                              hipStream_t stream) {
    (void)in_sizes; (void)n_in; (void)out_size; (void)ws_size;
    const float* xyz    = (const float*)d_in[0];
    const float* feats  = (const float*)d_in[1];
    const float* enc_W  = (const float*)d_in[2];
    const float* enc_b  = (const float*)d_in[3];
    const float* tb_Wq  = (const float*)d_in[4];
    const float* tb_Wk  = (const float*)d_in[5];
    const float* tb_Wv  = (const float*)d_in[6];
    const float* tb_Wg1 = (const float*)d_in[7];
    const float* tb_bg1 = (const float*)d_in[8];
    const float* tb_Wg2 = (const float*)d_in[9];
    const float* tb_bg2 = (const float*)d_in[10];
    const float* tb_Wpe = (const float*)d_in[11];
    const float* tb_bpe = (const float*)d_in[12];
    const float* tb_gamma = (const float*)d_in[13];
    const float* tb_beta  = (const float*)d_in[14];
    const float* em_W1  = (const float*)d_in[15];
    const float* em_b1  = (const float*)d_in[16];
    const float* em_W2  = (const float*)d_in[17];
    const float* em_b2  = (const float*)d_in[18];
    const float* em_gamma = (const float*)d_in[19];
    const float* em_beta  = (const float*)d_in[20];
    const float* fcf_W1 = (const float*)d_in[21];
    const float* fcf_b1 = (const float*)d_in[22];
    const float* fcf_W2 = (const float*)d_in[23];
    const float* fcf_b2 = (const float*)d_in[24];
    float* out = (float*)d_out;

    float* ws = (float*)d_ws;
    float* fbuf = ws;                      // ROWS_*D_
    float* gbuf = fbuf + ROWS_*D_;         // ROWS_*D_
    float* qbuf = gbuf + ROWS_*D_;
    float* kbuf = qbuf + ROWS_*D_;
    float* vbuf = kbuf + ROWS_*D_;
    float* ebuf = vbuf + ROWS_*D_;         // ROWS_*LAT_

    enc_kernel<<<(ROWS_*D_+255)/256, 256, 0, stream>>>(feats, enc_W, enc_b, fbuf);

    for (int i = 0; i < 3; i++) {
        const float* Wq  = tb_Wq  + i*D_*D_;
        const float* Wk  = tb_Wk  + i*D_*D_;
        const float* Wv  = tb_Wv  + i*D_*D_;
        const float* Wg1 = tb_Wg1 + i*D_*D_;
        const float* bg1 = tb_bg1 + i*D_;
        const float* Wg2 = tb_Wg2 + i*D_*D_;
        const float* bg2 = tb_bg2 + i*D_;
        const float* Wpe = tb_Wpe + i*D_*NPOS_;
        const float* bpe = tb_bpe + i*D_;

        qkv_kernel<<<ROWS_, 128, 0, stream>>>(fbuf, Wq, Wk, Wv, qbuf, kbuf, vbuf);
        attn_mfma_kernel<<<ROWS_, 512, 0, stream>>>(xyz, fbuf, qbuf, kbuf, vbuf,
                                                    Wpe, bpe, Wg1, bg1, Wg2, bg2, gbuf);
        bn_kernel<<<D_, 256, 0, stream>>>(gbuf, tb_gamma + i*D_, tb_beta + i*D_, fbuf);

        if (i > 0) {
            int j = i - 1;
            em_kernel<<<ROWS_, 128, 0, stream>>>(fbuf, em_W1 + j*D_*D_, em_b1 + j*D_,
                                                 em_W2 + j*D_*D_, em_b2 + j*D_, gbuf);
            bn_kernel<<<D_, 256, 0, stream>>>(gbuf, em_gamma + j*D_, em_beta + j*D_, fbuf);
        }
    }

    final_kernel<<<ROWS_, 256, 0, stream>>>(fbuf, fcf_W1, fcf_b1, fcf_W2, fcf_b2, ebuf);
    maxred_kernel<<<B_, 256, 0, stream>>>(ebuf, out);
}